// Round 15
// baseline (275.001 us; speedup 1.0000x reference)
//
#include <hip/hip_runtime.h>
#include <cstdint>

typedef __bf16 bf16x8 __attribute__((ext_vector_type(8)));
typedef float f32x4 __attribute__((ext_vector_type(4)));

#define DI __device__ __forceinline__

constexpr int NTOK = 4096;   // B*S
constexpr int HID  = 1024;
constexpr int IMO  = 512;    // moe intermediate
constexpr int NEXP = 16;
constexpr int SHI  = 1024;   // shared intermediate

// async global->LDS, 16B per lane, wave-uniform LDS base (m97/m193 pattern)
#define GLOAD_LDS(g, l) __builtin_amdgcn_global_load_lds( \
    (const __attribute__((address_space(1))) unsigned int*)(const void*)(g), \
    (__attribute__((address_space(3))) unsigned int*)(void*)(l), 16, 0, 0)

DI unsigned short f2bf(float f) {
  unsigned u = __float_as_uint(f);
  u = (u + 0x7fffu + ((u >> 16) & 1u)) >> 16;   // round-to-nearest-even
  return (unsigned short)u;
}
DI float bf2f(unsigned short b) { return __uint_as_float(((unsigned)b) << 16); }

// ---------------- init / prefix / scatter ----------------
__global__ void init_counts(int* __restrict__ counts) {
  if (threadIdx.x < NEXP) counts[threadIdx.x] = 0;
}

__global__ void prefix_kernel(const int* __restrict__ counts,
                              int* __restrict__ offsets, int* __restrict__ cursor) {
  if (threadIdx.x == 0 && blockIdx.x == 0) {
    int s = 0;
    for (int e = 0; e < NEXP; ++e) { offsets[e] = s; cursor[e] = s; s += counts[e]; }
    offsets[NEXP] = s;
  }
}

__global__ __launch_bounds__(256) void scatter_kernel(
    const int* __restrict__ topk_idx, int* __restrict__ cursor,
    int* __restrict__ perm, int* __restrict__ pos) {
  int i = blockIdx.x * 256 + threadIdx.x;   // over NTOK*4
  int e = topk_idx[i];
  int slot = atomicAdd(&cursor[e], 1);
  perm[slot] = i >> 2;
  pos[i] = slot;
}

// ---------------- merged gate + convert (round-15) ----------------
// blockIdx.x < 1024: gate (fp64 ranking; gw staged in LDS -- round-9-verified
// body, byte-identical). blockIdx.x >= 1024: fp32->bf16 convert of x + weights.
// The two jobs are independent (gate: x,gw,gb -> topk/counts; convert: weights
// -> bf16 copies), so merging overlaps a latency-bound kernel with a BW-bound
// one and removes a launch gap. Branch is block-uniform (no divergent barrier).
__global__ __launch_bounds__(256) void gate_convert(
    const float* __restrict__ x, const float* __restrict__ gw,
    const float* __restrict__ gb, int* __restrict__ topk_idx,
    float* __restrict__ topk_w, int* __restrict__ counts,
    const float* __restrict__ wg, const float* __restrict__ wu,
    const float* __restrict__ wd, const float* __restrict__ sg,
    const float* __restrict__ su, const float* __restrict__ sd,
    unsigned short* __restrict__ xb, unsigned short* __restrict__ wgb,
    unsigned short* __restrict__ wub, unsigned short* __restrict__ wdb,
    unsigned short* __restrict__ sgb, unsigned short* __restrict__ sub,
    unsigned short* __restrict__ sdb) {
  const int tid = threadIdx.x;
  if (blockIdx.x >= 1024) {
    // ---- convert job: float4 index over x + all weights (8126464 total) ----
    long g = (long)(blockIdx.x - 1024) * 256 + tid;
    const float* s; unsigned short* d; long o;
    if      (g < 1048576L) { s = x;  d = xb;  o = g; }
    else if (g < 3145728L) { s = wg; d = wgb; o = g - 1048576L; }
    else if (g < 5242880L) { s = wu; d = wub; o = g - 3145728L; }
    else if (g < 7340032L) { s = wd; d = wdb; o = g - 5242880L; }
    else if (g < 7602176L) { s = sg; d = sgb; o = g - 7340032L; }
    else if (g < 7864320L) { s = su; d = sub; o = g - 7602176L; }
    else                   { s = sd; d = sdb; o = g - 7864320L; }
    float4 v = ((const float4*)s)[o];
    ushort4 r;
    r.x = f2bf(v.x); r.y = f2bf(v.y); r.z = f2bf(v.z); r.w = f2bf(v.w);
    ((ushort4*)d)[o] = r;
    return;
  }
  // ---- gate job (round-9-verified body) ----
  __shared__ float gwl[16 * 1028];          // 65792 B
#pragma unroll
  for (int it = 0; it < 16; ++it) {
    int i4 = it * 256 + tid;                // float4 index in [0,4096)
    int row = i4 >> 8, col4 = i4 & 255;
    float4 v = ((const float4*)gw)[i4];
    *(float4*)(gwl + row * 1028 + col4 * 4) = v;
  }
  __syncthreads();

  const int lane = tid & 63;
  const int n = blockIdx.x * 4 + (tid >> 6);
  const int e = lane & 15;          // expert
  const int c = lane >> 4;          // chunk [0,4)
  const int g = e >> 2;             // group [0,4)

  const float4* x4 = (const float4*)(x + (size_t)n * HID + c * 256);
  const float4* w4 = (const float4*)(gwl + e * 1028 + c * 256);

  double acc0 = 0, acc1 = 0, acc2 = 0, acc3 = 0, acc4 = 0, acc5 = 0, acc6 = 0, acc7 = 0;
#pragma unroll
  for (int i = 0; i < 32; ++i) {
    float4 xa = x4[2 * i], xb2 = x4[2 * i + 1];
    float4 wa = w4[2 * i], wb = w4[2 * i + 1];
    acc0 += (double)xa.x * wa.x; acc1 += (double)xa.y * wa.y;
    acc2 += (double)xa.z * wa.z; acc3 += (double)xa.w * wa.w;
    acc4 += (double)xb2.x * wb.x; acc5 += (double)xb2.y * wb.y;
    acc6 += (double)xb2.z * wb.z; acc7 += (double)xb2.w * wb.w;
  }
  double L = ((acc0 + acc1) + (acc2 + acc3)) + ((acc4 + acc5) + (acc6 + acc7));
  L += __shfl_xor(L, 16);
  L += __shfl_xor(L, 32);

  double sig = 1.0 / (1.0 + exp(-L));
  double sfc = sig + (double)gb[e];

  // group score = sum of top-2 sfc within group of 4
  double o1 = __shfl_xor(sfc, 1);
  double hi = fmax(sfc, o1), lo = fmin(sfc, o1);
  double hi2 = __shfl_xor(hi, 2), lo2 = __shfl_xor(lo, 2);
  double gs = fmax(hi, hi2) + fmax(fmin(hi, hi2), fmax(lo, lo2));

  // rank my group among the 4 group scores (stable)
  double gsA = __shfl_xor(gs, 4);
  double gsB = __shfl_xor(gs, 8);
  double gsC = __shfl_xor(gs, 12);
  int grank = 0;
  grank += (gsA > gs || (gsA == gs && (g ^ 1) < g)) ? 1 : 0;
  grank += (gsB > gs || (gsB == gs && (g ^ 2) < g)) ? 1 : 0;
  grank += (gsC > gs || (gsC == gs && (g ^ 3) < g)) ? 1 : 0;
  const bool allowed = grank < 2;

  // expert rank among allowed, stable tie-break by index
  double sv = allowed ? sfc : -1e300;
  int rank = 0;
#pragma unroll
  for (int m = 1; m < 16; ++m) {
    double o = __shfl_xor(sv, m);
    int oe = e ^ m;
    rank += (o > sv || (o == sv && oe < e)) ? 1 : 0;
  }
  const bool chosen = allowed && (rank < 4);

  double t = chosen ? sig : 0.0;
  t += __shfl_xor(t, 1);
  t += __shfl_xor(t, 2);
  t += __shfl_xor(t, 4);
  t += __shfl_xor(t, 8);

  if (chosen && c == 0) {
    topk_idx[n * 4 + rank] = e;
    topk_w[n * 4 + rank] = (float)(sig / (t + 1e-20) * 2.5);
    atomicAdd(&counts[e], 1);
  }
}

// ---------------- merged bf16 MFMA GEMM level: routed job + shared job ----------------
// Round-15: K-loop is the round-13 depth-2 counted-vmcnt form VERBATIM (best
// measured 73.6/73.7 us; rounds 10/11/14 schedule variants all neutral/negative
// -- m233's 2-phase plateau is this structure's practical ceiling).
// GU: BM=256, BN=128x2 (g,u). Down: BN=256. Both: BUFB=32 KB, 4 DMA
// loads/wave/stage -> vmcnt(4) steady / 0 tail. XOR k-swizzle conflict-free
// (SQ_LDS_BANK_CONFLICT = 0 since round 6).
template <bool GU>
__global__ __launch_bounds__(512) void gemm_lvl(
    // routed job
    const unsigned short* __restrict__ Ar, const unsigned short* __restrict__ B0r,
    const unsigned short* __restrict__ B1r, unsigned short* __restrict__ Cr,
    int Kr, int ldcr, long eStrideB,
    const int* __restrict__ counts, const int* __restrict__ offsets,
    const int* __restrict__ perm, int useGather,
    // shared job
    const unsigned short* __restrict__ As, const unsigned short* __restrict__ B0s,
    const unsigned short* __restrict__ B1s, void* __restrict__ Cs,
    int Ms, int Ks, int ldcs, int nShared) {
  const int bx = blockIdx.x;
  const bool isShared = bx < nShared;
  int mt, y, cnt, off = 0, K, ldc;
  const unsigned short *A, *Bg, *Bu = nullptr;
  bool gather = false;
  if (isShared) {
    mt = bx & 15; y = bx >> 4;              // 16 mtiles(256) x ny
    cnt = Ms; K = Ks; ldc = ldcs;
    A = As; Bg = B0s;
    if constexpr (GU) Bu = B1s;
  } else {
    int r = bx - nShared;
    int e = ((r & 7) << 1) | ((r >> 3) & 1); // XCD (r&7) owns experts {2c,2c+1}
    mt = (r >> 4) & 15; y = r >> 8;
    cnt = counts[e]; off = offsets[e];
    if (mt * 256 >= cnt) return;
    K = Kr; ldc = ldcr;
    A = Ar; Bg = B0r + (long)e * eStrideB;
    if constexpr (GU) Bu = B1r + (long)e * eStrideB;
    gather = (useGather != 0);
  }
  const int n0 = y * (GU ? 128 : 256);

  const int tid = threadIdx.x;
  const int lane = tid & 63;
  const int wid = tid >> 6;                  // [0,8)
  const int wm = (wid >> 1) * 64;
  const int wn = (wid & 1) * (GU ? 64 : 128);

  constexpr int NI = GU ? 4 : 8;             // per-wave N fragments
  constexpr int ABYTES = 16384;              // A region: 256 rows x 32 shorts
  constexpr int BBYTES = GU ? 8192 : 16384;  // per B matrix region
  constexpr int BUFB = 32768;                // A + (g,u | B) = 32 KB both levels
  __shared__ __align__(16) unsigned char lds[2 * 32768];

  // ---- staging geometry (conflict-free both sides; rounds 6-13) ----
  // lane l of instr i: c = i*64+l, row = c>>2, kc = (c&3) ^ ((row>>1)&3).
  const unsigned short* aP[2]; int aD[2];
#pragma unroll
  for (int j = 0; j < 2; ++j) {
    int c = (wid * 2 + j) * 64 + lane;
    int row = c >> 2;
    int kc = (c & 3) ^ ((row >> 1) & 3);
    aD[j] = (wid * 2 + j) * 1024;
    int am = mt * 256 + row;
    int amc = am < cnt ? am : cnt - 1;
    long ar;
    if (isShared)    ar = amc;
    else if (gather) ar = perm[off + amc];
    else             ar = off + amc;
    aP[j] = A + ar * (long)K + kc * 8;
  }
  const unsigned short* gP[2]; const unsigned short* uP = nullptr;
  int bDj[2];
  if constexpr (GU) {
    int c = wid * 64 + lane;
    int row = c >> 2;                        // [0,128)
    int kc = (c & 3) ^ ((row >> 1) & 3);
    bDj[0] = wid * 1024;
    gP[0] = Bg + (long)(n0 + row) * K + kc * 8;
    uP    = Bu + (long)(n0 + row) * K + kc * 8;
  } else {
#pragma unroll
    for (int j = 0; j < 2; ++j) {
      int c = (wid * 2 + j) * 64 + lane;
      int row = c >> 2;                      // [0,256)
      int kc = (c & 3) ^ ((row >> 1) & 3);
      bDj[j] = (wid * 2 + j) * 1024;
      gP[j] = Bg + (long)(n0 + row) * K + kc * 8;
    }
  }

  auto STAGE = [&](int buf, int t) {
    unsigned char* base = lds + buf * BUFB;
    const int koff = t * 32;                 // shorts
    GLOAD_LDS(aP[0] + koff, base + aD[0]);
    GLOAD_LDS(aP[1] + koff, base + aD[1]);
    if constexpr (GU) {
      GLOAD_LDS(gP[0] + koff, base + ABYTES + bDj[0]);
      GLOAD_LDS(uP + koff, base + ABYTES + BBYTES + bDj[0]);
    } else {
      GLOAD_LDS(gP[0] + koff, base + ABYTES + bDj[0]);
      GLOAD_LDS(gP[1] + koff, base + ABYTES + bDj[1]);
    }
  };

  f32x4 accg[4][NI];
  f32x4 accu[GU ? 4 : 1][GU ? 4 : 1];
#pragma unroll
  for (int a = 0; a < 4; ++a) {
#pragma unroll
    for (int b = 0; b < NI; ++b) accg[a][b] = f32x4{0.f, 0.f, 0.f, 0.f};
    if constexpr (GU) {
#pragma unroll
      for (int b = 0; b < 4; ++b) accu[a][b] = f32x4{0.f, 0.f, 0.f, 0.f};
    }
  }

  const int r16 = lane & 15, kc4 = lane >> 4;
  const int kq = (kc4 ^ ((r16 >> 1) & 3)) * 8;   // swizzled k-chunk (shorts)
  auto COMPUTE = [&](int buf) {
    const unsigned short* bA = (const unsigned short*)(lds + buf * BUFB);
    const unsigned short* bG = bA + ABYTES / 2;
    const unsigned short* bU = bG + BBYTES / 2;   // GU only
    bf16x8 af[4], fr[NI], uf[4];
#pragma unroll
    for (int mi = 0; mi < 4; ++mi)
      af[mi] = *(const bf16x8*)(bA + (wm + mi * 16 + r16) * 32 + kq);
#pragma unroll
    for (int ni = 0; ni < NI; ++ni)
      fr[ni] = *(const bf16x8*)(bG + (wn + ni * 16 + r16) * 32 + kq);
    if constexpr (GU) {
#pragma unroll
      for (int ni = 0; ni < 4; ++ni)
        uf[ni] = *(const bf16x8*)(bU + (wn + ni * 16 + r16) * 32 + kq);
    }
#pragma unroll
    for (int mi = 0; mi < 4; ++mi)
#pragma unroll
      for (int ni = 0; ni < NI; ++ni) {
        accg[mi][ni] = __builtin_amdgcn_mfma_f32_16x16x32_bf16(af[mi], fr[ni], accg[mi][ni], 0, 0, 0);
        if constexpr (GU)
          accu[mi][ni] = __builtin_amdgcn_mfma_f32_16x16x32_bf16(af[mi], uf[ni], accu[mi][ni], 0, 0, 0);
      }
  };

  // ---- depth-2 pipeline, counted vmcnt (4 loads/wave/stage both levels) ----
  const int NT = K >> 5;
  STAGE(0, 0);
  STAGE(1, 1);
  int cur = 0;
  for (int t = 0; t < NT; ++t) {
    if (t + 1 < NT) asm volatile("s_waitcnt vmcnt(4)" ::: "memory");
    else            asm volatile("s_waitcnt vmcnt(0)" ::: "memory");
    __builtin_amdgcn_s_barrier();        // all waves' tile-t loads now visible
    COMPUTE(cur);
    __builtin_amdgcn_s_barrier();        // all waves done reading buf cur
    if (t + 2 < NT) STAGE(cur, t + 2);   // refill freed buffer
    cur ^= 1;
  }

  // epilogue: C layout col=lane&15, row=(lane>>4)*4+reg  [m89-verified]
#pragma unroll
  for (int mi = 0; mi < 4; ++mi)
#pragma unroll
    for (int ni = 0; ni < NI; ++ni)
#pragma unroll
      for (int j = 0; j < 4; ++j) {
        int r = wm + mi * 16 + kc4 * 4 + j;
        int gr = mt * 256 + r;
        if (gr < cnt) {
          int c = n0 + wn + ni * 16 + r16;
          if constexpr (GU) {
            float g = accg[mi][ni][j], u = accu[mi][ni][j];
            float sg = g / (1.f + __expf(-g));       // silu
            unsigned short v = f2bf(sg * u);
            if (isShared) ((unsigned short*)Cs)[(long)gr * ldc + c] = v;
            else          Cr[((long)off + gr) * ldc + c] = v;
          } else {
            if (isShared) ((float*)Cs)[(long)gr * ldc + c] = accg[mi][ni][j];
            else          Cr[((long)off + gr) * ldc + c] = f2bf(accg[mi][ni][j]);
          }
        }
      }
}

// ---------------- final combine: out = x + shared(in d_out) + sum_k w_k*yout ----------------
__global__ __launch_bounds__(256) void combine_kernel(
    const float* __restrict__ x, const float* __restrict__ sh,
    const unsigned short* __restrict__ yout, const float* __restrict__ tw,
    const int* __restrict__ pos, float* __restrict__ out) {
  int n = blockIdx.x;                  // one block per token
  int h4 = threadIdx.x << 2;           // 256 threads * 4 floats = 1024
  float4 xv = *(const float4*)(x + (long)n * HID + h4);
  float4 sv = *(const float4*)(sh + (long)n * HID + h4);   // shared-expert result (read before write)
  float a0 = xv.x + sv.x, a1 = xv.y + sv.y, a2 = xv.z + sv.z, a3 = xv.w + sv.w;
#pragma unroll
  for (int k = 0; k < 4; ++k) {
    float w = tw[n * 4 + k];
    long slot = pos[n * 4 + k];
    ushort4 yv = *(const ushort4*)(yout + slot * HID + h4);
    a0 += w * bf2f(yv.x); a1 += w * bf2f(yv.y);
    a2 += w * bf2f(yv.z); a3 += w * bf2f(yv.w);
  }
  float4 o; o.x = a0; o.y = a1; o.z = a2; o.w = a3;
  *(float4*)(out + (long)n * HID + h4) = o;
}

// ---------------- launch ----------------
extern "C" void kernel_launch(void* const* d_in, const int* in_sizes, int n_in,
                              void* d_out, int out_size, void* d_ws, size_t ws_size,
                              hipStream_t stream) {
  (void)in_sizes; (void)n_in; (void)out_size; (void)ws_size;
  const float* x   = (const float*)d_in[0];
  const float* gw  = (const float*)d_in[1];
  const float* gb  = (const float*)d_in[2];
  const float* Wg  = (const float*)d_in[3];
  const float* Wu  = (const float*)d_in[4];
  const float* Wd  = (const float*)d_in[5];
  const float* Wsg = (const float*)d_in[6];
  const float* Wsu = (const float*)d_in[7];
  const float* Wsd = (const float*)d_in[8];
  float* out = (float*)d_out;

  // ---- workspace layout (big buffers start at 512 KiB; small region ends 262400) ----
  char* w = (char*)d_ws;
  int*   counts   = (int*)(w + 0);                    // 64 B
  int*   cursor   = (int*)(w + 64);                   // 64 B
  int*   offsets  = (int*)(w + 128);                  // 128 B (17 ints)
  int*   topk_idx = (int*)(w + 256);                  // 65536 B
  float* topk_w   = (float*)(w + 256 + 65536);        // 65536 B
  int*   perm     = (int*)(w + 256 + 131072);         // 65536 B
  int*   pos      = (int*)(w + 256 + 196608);         // 65536 B
  size_t o = 524288;                                  // big buffers from 512 KiB
  unsigned short* xb   = (unsigned short*)(w + o); o += (size_t)NTOK * HID * 2;       // 8 MB
  unsigned short* WgB  = (unsigned short*)(w + o); o += (size_t)NEXP * IMO * HID * 2; // 16 MB
  unsigned short* WuB  = (unsigned short*)(w + o); o += (size_t)NEXP * IMO * HID * 2; // 16 MB
  unsigned short* WdB  = (unsigned short*)(w + o); o += (size_t)NEXP * HID * IMO * 2; // 16 MB
  unsigned short* WsgB = (unsigned short*)(w + o); o += (size_t)SHI * HID * 2;        // 2 MB
  unsigned short* WsuB = (unsigned short*)(w + o); o += (size_t)SHI * HID * 2;        // 2 MB
  unsigned short* WsdB = (unsigned short*)(w + o); o += (size_t)HID * SHI * 2;        // 2 MB
  unsigned short* act  = (unsigned short*)(w + o); o += (size_t)NTOK * 4 * IMO * 2;   // 16 MB
  unsigned short* yout = (unsigned short*)(w + o); o += (size_t)NTOK * 4 * HID * 2;   // 32 MB
  unsigned short* sact = (unsigned short*)(w + o); o += (size_t)NTOK * SHI * 2;       // 8 MB
  // total ws use ~118.5 MiB; shared-expert fp32 output goes directly to d_out

  init_counts<<<1, 64, 0, stream>>>(counts);
  // merged gate (blocks 0..1023) + convert (blocks 1024..32767)
  gate_convert<<<1024 + 31744, 256, 0, stream>>>(
      x, gw, gb, topk_idx, topk_w, counts,
      Wg, Wu, Wd, Wsg, Wsu, Wsd,
      xb, WgB, WuB, WdB, WsgB, WsuB, WsdB);
  prefix_kernel<<<1, 64, 0, stream>>>(counts, offsets, cursor);
  scatter_kernel<<<NTOK * 4 / 256, 256, 0, stream>>>(topk_idx, cursor, perm, pos);
  // Level 1: shared gate+up (128 blocks: 16 mt x 8 y) + routed gate+up
  // (1024 slots: e,mt 256 x ny 4), BN=128 per matrix, 512 threads/block.
  gemm_lvl<true><<<128 + 1024, 512, 0, stream>>>(
      xb, WgB, WuB, act, HID, IMO, (long)IMO * HID, counts, offsets, perm, 1,
      xb, WsgB, WsuB, sact, NTOK, HID, SHI, 128);
  // Level 2: shared down (64 blocks: 16 mt x 4 y) + routed down
  // (1024 slots: e,mt 256 x ny 4), BN=256.
  gemm_lvl<false><<<64 + 1024, 512, 0, stream>>>(
      act, WdB, nullptr, yout, IMO, HID, (long)HID * IMO, counts, offsets, nullptr, 0,
      sact, WsdB, nullptr, out, NTOK, SHI, HID, 64);
  // out = x + shared + sum_k w_k * yout[pos]
  combine_kernel<<<NTOK, 256, 0, stream>>>(x, out, yout, topk_w, pos, out);
}

// Round 16
// 265.870 us; speedup vs baseline: 1.0343x; 1.0343x over previous
//
#include <hip/hip_runtime.h>
#include <cstdint>

typedef __bf16 bf16x8 __attribute__((ext_vector_type(8)));
typedef float f32x4 __attribute__((ext_vector_type(4)));

#define DI __device__ __forceinline__

constexpr int NTOK = 4096;   // B*S
constexpr int HID  = 1024;
constexpr int IMO  = 512;    // moe intermediate
constexpr int NEXP = 16;
constexpr int SHI  = 1024;   // shared intermediate

// async global->LDS, 16B per lane, wave-uniform LDS base (m97/m193 pattern)
#define GLOAD_LDS(g, l) __builtin_amdgcn_global_load_lds( \
    (const __attribute__((address_space(1))) unsigned int*)(const void*)(g), \
    (__attribute__((address_space(3))) unsigned int*)(void*)(l), 16, 0, 0)

DI unsigned short f2bf(float f) {
  unsigned u = __float_as_uint(f);
  u = (u + 0x7fffu + ((u >> 16) & 1u)) >> 16;   // round-to-nearest-even
  return (unsigned short)u;
}
DI float bf2f(unsigned short b) { return __uint_as_float(((unsigned)b) << 16); }

// ---------------- init / prefix / scatter ----------------
__global__ void init_counts(int* __restrict__ counts) {
  if (threadIdx.x < NEXP) counts[threadIdx.x] = 0;
}

__global__ void prefix_kernel(const int* __restrict__ counts,
                              int* __restrict__ offsets, int* __restrict__ cursor) {
  if (threadIdx.x == 0 && blockIdx.x == 0) {
    int s = 0;
    for (int e = 0; e < NEXP; ++e) { offsets[e] = s; cursor[e] = s; s += counts[e]; }
    offsets[NEXP] = s;
  }
}

__global__ __launch_bounds__(256) void scatter_kernel(
    const int* __restrict__ topk_idx, int* __restrict__ cursor,
    int* __restrict__ perm, int* __restrict__ pos) {
  int i = blockIdx.x * 256 + threadIdx.x;   // over NTOK*4
  int e = topk_idx[i];
  int slot = atomicAdd(&cursor[e], 1);
  perm[slot] = i >> 2;
  pos[i] = slot;
}

// ---------------- gate (fp64 ranking; gw staged in LDS) -- round-9-verified ----------------
// Round-16: back to a STANDALONE kernel. Round-15's merge with convert made every
// convert block reserve gate's 66KB LDS -> 2 blocks/CU for a streaming kernel ->
// 1.1 TB/s. Static LDS is per-kernel: never merge big-LDS + BW-streaming jobs.
__global__ __launch_bounds__(256) void gate_kernel(
    const float* __restrict__ x, const float* __restrict__ gw,
    const float* __restrict__ gb, int* __restrict__ topk_idx,
    float* __restrict__ topk_w, int* __restrict__ counts) {
  __shared__ float gwl[16 * 1028];          // 65792 B
  const int tid = threadIdx.x;
#pragma unroll
  for (int it = 0; it < 16; ++it) {
    int i4 = it * 256 + tid;                // float4 index in [0,4096)
    int row = i4 >> 8, col4 = i4 & 255;
    float4 v = ((const float4*)gw)[i4];
    *(float4*)(gwl + row * 1028 + col4 * 4) = v;
  }
  __syncthreads();

  const int lane = tid & 63;
  const int n = blockIdx.x * 4 + (tid >> 6);
  const int e = lane & 15;          // expert
  const int c = lane >> 4;          // chunk [0,4)
  const int g = e >> 2;             // group [0,4)

  const float4* x4 = (const float4*)(x + (size_t)n * HID + c * 256);
  const float4* w4 = (const float4*)(gwl + e * 1028 + c * 256);

  double acc0 = 0, acc1 = 0, acc2 = 0, acc3 = 0, acc4 = 0, acc5 = 0, acc6 = 0, acc7 = 0;
#pragma unroll
  for (int i = 0; i < 32; ++i) {
    float4 xa = x4[2 * i], xb = x4[2 * i + 1];
    float4 wa = w4[2 * i], wb = w4[2 * i + 1];
    acc0 += (double)xa.x * wa.x; acc1 += (double)xa.y * wa.y;
    acc2 += (double)xa.z * wa.z; acc3 += (double)xa.w * wa.w;
    acc4 += (double)xb.x * wb.x; acc5 += (double)xb.y * wb.y;
    acc6 += (double)xb.z * wb.z; acc7 += (double)xb.w * wb.w;
  }
  double L = ((acc0 + acc1) + (acc2 + acc3)) + ((acc4 + acc5) + (acc6 + acc7));
  L += __shfl_xor(L, 16);
  L += __shfl_xor(L, 32);

  double sig = 1.0 / (1.0 + exp(-L));
  double sfc = sig + (double)gb[e];

  double o1 = __shfl_xor(sfc, 1);
  double hi = fmax(sfc, o1), lo = fmin(sfc, o1);
  double hi2 = __shfl_xor(hi, 2), lo2 = __shfl_xor(lo, 2);
  double gs = fmax(hi, hi2) + fmax(fmin(hi, hi2), fmax(lo, lo2));

  double gsA = __shfl_xor(gs, 4);
  double gsB = __shfl_xor(gs, 8);
  double gsC = __shfl_xor(gs, 12);
  int grank = 0;
  grank += (gsA > gs || (gsA == gs && (g ^ 1) < g)) ? 1 : 0;
  grank += (gsB > gs || (gsB == gs && (g ^ 2) < g)) ? 1 : 0;
  grank += (gsC > gs || (gsC == gs && (g ^ 3) < g)) ? 1 : 0;
  const bool allowed = grank < 2;

  double sv = allowed ? sfc : -1e300;
  int rank = 0;
#pragma unroll
  for (int m = 1; m < 16; ++m) {
    double o = __shfl_xor(sv, m);
    int oe = e ^ m;
    rank += (o > sv || (o == sv && oe < e)) ? 1 : 0;
  }
  const bool chosen = allowed && (rank < 4);

  double t = chosen ? sig : 0.0;
  t += __shfl_xor(t, 1);
  t += __shfl_xor(t, 2);
  t += __shfl_xor(t, 4);
  t += __shfl_xor(t, 8);

  if (chosen && c == 0) {
    topk_idx[n * 4 + rank] = e;
    topk_w[n * 4 + rank] = (float)(sig / (t + 1e-20) * 2.5);
    atomicAdd(&counts[e], 1);
  }
}

// ---------------- fp32 -> bf16 convert: x + L1 weights only ----------------
// Round-16: Wd/Wsd conversion moved into the L1 GEMM launch as trailing blocks
// (they're only needed by L2; L1 leaves ~85% of HBM BW idle).
__global__ __launch_bounds__(256) void convert_l1(
    const float* __restrict__ x, const float* __restrict__ wg,
    const float* __restrict__ wu, const float* __restrict__ sg,
    const float* __restrict__ su,
    unsigned short* __restrict__ xb, unsigned short* __restrict__ wgb,
    unsigned short* __restrict__ wub, unsigned short* __restrict__ sgb,
    unsigned short* __restrict__ sub) {
  long g = (long)blockIdx.x * 256 + threadIdx.x;   // float4 index, total 5767168
  const float* s; unsigned short* d; long o;
  if      (g < 1048576L) { s = x;  d = xb;  o = g; }
  else if (g < 3145728L) { s = wg; d = wgb; o = g - 1048576L; }
  else if (g < 5242880L) { s = wu; d = wub; o = g - 3145728L; }
  else if (g < 5505024L) { s = sg; d = sgb; o = g - 5242880L; }
  else                   { s = su; d = sub; o = g - 5505024L; }
  float4 v = ((const float4*)s)[o];
  ushort4 r;
  r.x = f2bf(v.x); r.y = f2bf(v.y); r.z = f2bf(v.z); r.w = f2bf(v.w);
  ((ushort4*)d)[o] = r;
}

// ---------------- merged bf16 MFMA GEMM level: routed job + shared job ----------------
// K-loop: round-13 depth-2 counted-vmcnt form VERBATIM (best measured 73.6/73.7us;
// rounds 10/11/14 schedule variants all neutral/negative -- 2-phase plateau).
// GU: BM=256, BN=128x2 (g,u). Down: BN=256. Both: BUFB=32 KB, 4 DMA
// loads/wave/stage -> vmcnt(4) steady / 0 tail. XOR k-swizzle conflict-free.
// Round-16 (GU only): trailing blocks (bx >= nGemmBlocks) convert Wd/Wsd
// fp32->bf16, riding L1's idle HBM BW. They return before any LDS/barrier use.
template <bool GU>
__global__ __launch_bounds__(512) void gemm_lvl(
    // routed job
    const unsigned short* __restrict__ Ar, const unsigned short* __restrict__ B0r,
    const unsigned short* __restrict__ B1r, unsigned short* __restrict__ Cr,
    int Kr, int ldcr, long eStrideB,
    const int* __restrict__ counts, const int* __restrict__ offsets,
    const int* __restrict__ perm, int useGather,
    // shared job
    const unsigned short* __restrict__ As, const unsigned short* __restrict__ B0s,
    const unsigned short* __restrict__ B1s, void* __restrict__ Cs,
    int Ms, int Ks, int ldcs, int nShared,
    // convert tail (GU only)
    const float* __restrict__ cvt0, const float* __restrict__ cvt1,
    unsigned short* __restrict__ cvt0b, unsigned short* __restrict__ cvt1b,
    int nGemmBlocks) {
  const int bx = blockIdx.x;
  if constexpr (GU) {
    if (bx >= nGemmBlocks) {
      // convert job: Wd (2097152 float4) then Wsd (262144 float4)
      long g = (long)(bx - nGemmBlocks) * 512 + threadIdx.x;
      const float* s; unsigned short* d; long o2;
      if (g < 2097152L) { s = cvt0; d = cvt0b; o2 = g; }
      else              { s = cvt1; d = cvt1b; o2 = g - 2097152L; }
      float4 v = ((const float4*)s)[o2];
      ushort4 r2;
      r2.x = f2bf(v.x); r2.y = f2bf(v.y); r2.z = f2bf(v.z); r2.w = f2bf(v.w);
      ((ushort4*)d)[o2] = r2;
      return;
    }
  }
  const bool isShared = bx < nShared;
  int mt, y, cnt, off = 0, K, ldc;
  const unsigned short *A, *Bg, *Bu = nullptr;
  bool gather = false;
  if (isShared) {
    mt = bx & 15; y = bx >> 4;              // 16 mtiles(256) x ny
    cnt = Ms; K = Ks; ldc = ldcs;
    A = As; Bg = B0s;
    if constexpr (GU) Bu = B1s;
  } else {
    int r = bx - nShared;
    int e = ((r & 7) << 1) | ((r >> 3) & 1); // XCD (r&7) owns experts {2c,2c+1}
    mt = (r >> 4) & 15; y = r >> 8;
    cnt = counts[e]; off = offsets[e];
    if (mt * 256 >= cnt) return;
    K = Kr; ldc = ldcr;
    A = Ar; Bg = B0r + (long)e * eStrideB;
    if constexpr (GU) Bu = B1r + (long)e * eStrideB;
    gather = (useGather != 0);
  }
  const int n0 = y * (GU ? 128 : 256);

  const int tid = threadIdx.x;
  const int lane = tid & 63;
  const int wid = tid >> 6;                  // [0,8)
  const int wm = (wid >> 1) * 64;
  const int wn = (wid & 1) * (GU ? 64 : 128);

  constexpr int NI = GU ? 4 : 8;             // per-wave N fragments
  constexpr int ABYTES = 16384;              // A region: 256 rows x 32 shorts
  constexpr int BBYTES = GU ? 8192 : 16384;  // per B matrix region
  constexpr int BUFB = 32768;                // A + (g,u | B) = 32 KB both levels
  __shared__ __align__(16) unsigned char lds[2 * 32768];

  // ---- staging geometry (conflict-free both sides; rounds 6-13) ----
  // lane l of instr i: c = i*64+l, row = c>>2, kc = (c&3) ^ ((row>>1)&3).
  const unsigned short* aP[2]; int aD[2];
#pragma unroll
  for (int j = 0; j < 2; ++j) {
    int c = (wid * 2 + j) * 64 + lane;
    int row = c >> 2;
    int kc = (c & 3) ^ ((row >> 1) & 3);
    aD[j] = (wid * 2 + j) * 1024;
    int am = mt * 256 + row;
    int amc = am < cnt ? am : cnt - 1;
    long ar;
    if (isShared)    ar = amc;
    else if (gather) ar = perm[off + amc];
    else             ar = off + amc;
    aP[j] = A + ar * (long)K + kc * 8;
  }
  const unsigned short* gP[2]; const unsigned short* uP = nullptr;
  int bDj[2];
  if constexpr (GU) {
    int c = wid * 64 + lane;
    int row = c >> 2;                        // [0,128)
    int kc = (c & 3) ^ ((row >> 1) & 3);
    bDj[0] = wid * 1024;
    gP[0] = Bg + (long)(n0 + row) * K + kc * 8;
    uP    = Bu + (long)(n0 + row) * K + kc * 8;
  } else {
#pragma unroll
    for (int j = 0; j < 2; ++j) {
      int c = (wid * 2 + j) * 64 + lane;
      int row = c >> 2;                      // [0,256)
      int kc = (c & 3) ^ ((row >> 1) & 3);
      bDj[j] = (wid * 2 + j) * 1024;
      gP[j] = Bg + (long)(n0 + row) * K + kc * 8;
    }
  }

  auto STAGE = [&](int buf, int t) {
    unsigned char* base = lds + buf * BUFB;
    const int koff = t * 32;                 // shorts
    GLOAD_LDS(aP[0] + koff, base + aD[0]);
    GLOAD_LDS(aP[1] + koff, base + aD[1]);
    if constexpr (GU) {
      GLOAD_LDS(gP[0] + koff, base + ABYTES + bDj[0]);
      GLOAD_LDS(uP + koff, base + ABYTES + BBYTES + bDj[0]);
    } else {
      GLOAD_LDS(gP[0] + koff, base + ABYTES + bDj[0]);
      GLOAD_LDS(gP[1] + koff, base + ABYTES + bDj[1]);
    }
  };

  f32x4 accg[4][NI];
  f32x4 accu[GU ? 4 : 1][GU ? 4 : 1];
#pragma unroll
  for (int a = 0; a < 4; ++a) {
#pragma unroll
    for (int b = 0; b < NI; ++b) accg[a][b] = f32x4{0.f, 0.f, 0.f, 0.f};
    if constexpr (GU) {
#pragma unroll
      for (int b = 0; b < 4; ++b) accu[a][b] = f32x4{0.f, 0.f, 0.f, 0.f};
    }
  }

  const int r16 = lane & 15, kc4 = lane >> 4;
  const int kq = (kc4 ^ ((r16 >> 1) & 3)) * 8;   // swizzled k-chunk (shorts)
  auto COMPUTE = [&](int buf) {
    const unsigned short* bA = (const unsigned short*)(lds + buf * BUFB);
    const unsigned short* bG = bA + ABYTES / 2;
    const unsigned short* bU = bG + BBYTES / 2;   // GU only
    bf16x8 af[4], fr[NI], uf[4];
#pragma unroll
    for (int mi = 0; mi < 4; ++mi)
      af[mi] = *(const bf16x8*)(bA + (wm + mi * 16 + r16) * 32 + kq);
#pragma unroll
    for (int ni = 0; ni < NI; ++ni)
      fr[ni] = *(const bf16x8*)(bG + (wn + ni * 16 + r16) * 32 + kq);
    if constexpr (GU) {
#pragma unroll
      for (int ni = 0; ni < 4; ++ni)
        uf[ni] = *(const bf16x8*)(bU + (wn + ni * 16 + r16) * 32 + kq);
    }
#pragma unroll
    for (int mi = 0; mi < 4; ++mi)
#pragma unroll
      for (int ni = 0; ni < NI; ++ni) {
        accg[mi][ni] = __builtin_amdgcn_mfma_f32_16x16x32_bf16(af[mi], fr[ni], accg[mi][ni], 0, 0, 0);
        if constexpr (GU)
          accu[mi][ni] = __builtin_amdgcn_mfma_f32_16x16x32_bf16(af[mi], uf[ni], accu[mi][ni], 0, 0, 0);
      }
  };

  // ---- depth-2 pipeline, counted vmcnt (4 loads/wave/stage both levels) ----
  const int NT = K >> 5;
  STAGE(0, 0);
  STAGE(1, 1);
  int cur = 0;
  for (int t = 0; t < NT; ++t) {
    if (t + 1 < NT) asm volatile("s_waitcnt vmcnt(4)" ::: "memory");
    else            asm volatile("s_waitcnt vmcnt(0)" ::: "memory");
    __builtin_amdgcn_s_barrier();        // all waves' tile-t loads now visible
    COMPUTE(cur);
    __builtin_amdgcn_s_barrier();        // all waves done reading buf cur
    if (t + 2 < NT) STAGE(cur, t + 2);   // refill freed buffer
    cur ^= 1;
  }

  // epilogue: C layout col=lane&15, row=(lane>>4)*4+reg  [m89-verified]
#pragma unroll
  for (int mi = 0; mi < 4; ++mi)
#pragma unroll
    for (int ni = 0; ni < NI; ++ni)
#pragma unroll
      for (int j = 0; j < 4; ++j) {
        int r = wm + mi * 16 + kc4 * 4 + j;
        int gr = mt * 256 + r;
        if (gr < cnt) {
          int c = n0 + wn + ni * 16 + r16;
          if constexpr (GU) {
            float g = accg[mi][ni][j], u = accu[mi][ni][j];
            float sg = g / (1.f + __expf(-g));       // silu
            unsigned short v = f2bf(sg * u);
            if (isShared) ((unsigned short*)Cs)[(long)gr * ldc + c] = v;
            else          Cr[((long)off + gr) * ldc + c] = v;
          } else {
            if (isShared) ((float*)Cs)[(long)gr * ldc + c] = accg[mi][ni][j];
            else          Cr[((long)off + gr) * ldc + c] = f2bf(accg[mi][ni][j]);
          }
        }
      }
}

// ---------------- final combine: out = x + shared(in d_out) + sum_k w_k*yout ----------------
__global__ __launch_bounds__(256) void combine_kernel(
    const float* __restrict__ x, const float* __restrict__ sh,
    const unsigned short* __restrict__ yout, const float* __restrict__ tw,
    const int* __restrict__ pos, float* __restrict__ out) {
  int n = blockIdx.x;                  // one block per token
  int h4 = threadIdx.x << 2;           // 256 threads * 4 floats = 1024
  float4 xv = *(const float4*)(x + (long)n * HID + h4);
  float4 sv = *(const float4*)(sh + (long)n * HID + h4);   // shared-expert result (read before write)
  float a0 = xv.x + sv.x, a1 = xv.y + sv.y, a2 = xv.z + sv.z, a3 = xv.w + sv.w;
#pragma unroll
  for (int k = 0; k < 4; ++k) {
    float w = tw[n * 4 + k];
    long slot = pos[n * 4 + k];
    ushort4 yv = *(const ushort4*)(yout + slot * HID + h4);
    a0 += w * bf2f(yv.x); a1 += w * bf2f(yv.y);
    a2 += w * bf2f(yv.z); a3 += w * bf2f(yv.w);
  }
  float4 o; o.x = a0; o.y = a1; o.z = a2; o.w = a3;
  *(float4*)(out + (long)n * HID + h4) = o;
}

// ---------------- launch ----------------
extern "C" void kernel_launch(void* const* d_in, const int* in_sizes, int n_in,
                              void* d_out, int out_size, void* d_ws, size_t ws_size,
                              hipStream_t stream) {
  (void)in_sizes; (void)n_in; (void)out_size; (void)ws_size;
  const float* x   = (const float*)d_in[0];
  const float* gw  = (const float*)d_in[1];
  const float* gb  = (const float*)d_in[2];
  const float* Wg  = (const float*)d_in[3];
  const float* Wu  = (const float*)d_in[4];
  const float* Wd  = (const float*)d_in[5];
  const float* Wsg = (const float*)d_in[6];
  const float* Wsu = (const float*)d_in[7];
  const float* Wsd = (const float*)d_in[8];
  float* out = (float*)d_out;

  // ---- workspace layout (big buffers start at 512 KiB; small region ends 262400) ----
  char* w = (char*)d_ws;
  int*   counts   = (int*)(w + 0);                    // 64 B
  int*   cursor   = (int*)(w + 64);                   // 64 B
  int*   offsets  = (int*)(w + 128);                  // 128 B (17 ints)
  int*   topk_idx = (int*)(w + 256);                  // 65536 B
  float* topk_w   = (float*)(w + 256 + 65536);        // 65536 B
  int*   perm     = (int*)(w + 256 + 131072);         // 65536 B
  int*   pos      = (int*)(w + 256 + 196608);         // 65536 B
  size_t o = 524288;                                  // big buffers from 512 KiB
  unsigned short* xb   = (unsigned short*)(w + o); o += (size_t)NTOK * HID * 2;       // 8 MB
  unsigned short* WgB  = (unsigned short*)(w + o); o += (size_t)NEXP * IMO * HID * 2; // 16 MB
  unsigned short* WuB  = (unsigned short*)(w + o); o += (size_t)NEXP * IMO * HID * 2; // 16 MB
  unsigned short* WdB  = (unsigned short*)(w + o); o += (size_t)NEXP * HID * IMO * 2; // 16 MB
  unsigned short* WsgB = (unsigned short*)(w + o); o += (size_t)SHI * HID * 2;        // 2 MB
  unsigned short* WsuB = (unsigned short*)(w + o); o += (size_t)SHI * HID * 2;        // 2 MB
  unsigned short* WsdB = (unsigned short*)(w + o); o += (size_t)HID * SHI * 2;        // 2 MB
  unsigned short* act  = (unsigned short*)(w + o); o += (size_t)NTOK * 4 * IMO * 2;   // 16 MB
  unsigned short* yout = (unsigned short*)(w + o); o += (size_t)NTOK * 4 * HID * 2;   // 32 MB
  unsigned short* sact = (unsigned short*)(w + o); o += (size_t)NTOK * SHI * 2;       // 8 MB
  // total ws use ~118.5 MiB; shared-expert fp32 output goes directly to d_out

  init_counts<<<1, 64, 0, stream>>>(counts);
  gate_kernel<<<NTOK / 4, 256, 0, stream>>>(x, gw, gb, topk_idx, topk_w, counts);
  prefix_kernel<<<1, 64, 0, stream>>>(counts, offsets, cursor);
  scatter_kernel<<<NTOK * 4 / 256, 256, 0, stream>>>(topk_idx, cursor, perm, pos);
  // convert x + L1 weights only (5767168 float4s)
  convert_l1<<<22528, 256, 0, stream>>>(x, Wg, Wu, Wsg, Wsu,
                                        xb, WgB, WuB, WsgB, WsuB);
  // Level 1: shared gate+up (128) + routed gate+up (1024) + Wd/Wsd convert tail
  // (4608 blocks x 512 thr x 1 float4 = 2359296 float4s).
  gemm_lvl<true><<<128 + 1024 + 4608, 512, 0, stream>>>(
      xb, WgB, WuB, act, HID, IMO, (long)IMO * HID, counts, offsets, perm, 1,
      xb, WsgB, WsuB, sact, NTOK, HID, SHI, 128,
      Wd, Wsd, WdB, WsdB, 128 + 1024);
  // Level 2: shared down (64 blocks: 16 mt x 4 y) + routed down
  // (1024 slots: e,mt 256 x ny 4), BN=256.
  gemm_lvl<false><<<64 + 1024, 512, 0, stream>>>(
      act, WdB, nullptr, yout, IMO, HID, (long)HID * IMO, counts, offsets, nullptr, 0,
      sact, WsdB, nullptr, out, NTOK, SHI, HID, 64,
      nullptr, nullptr, nullptr, nullptr, 1 << 30);
  // out = x + shared + sum_k w_k * yout[pos]
  combine_kernel<<<NTOK, 256, 0, stream>>>(x, out, yout, topk_w, pos, out);
}

// Round 17
// 188.947 us; speedup vs baseline: 1.4554x; 1.4071x over previous
//
#include <hip/hip_runtime.h>
#include <cstdint>

typedef __bf16 bf16x8 __attribute__((ext_vector_type(8)));
typedef float f32x4 __attribute__((ext_vector_type(4)));

#define DI __device__ __forceinline__

constexpr int NTOK = 4096;   // B*S
constexpr int HID  = 1024;
constexpr int IMO  = 512;    // moe intermediate
constexpr int NEXP = 16;
constexpr int SHI  = 1024;   // shared intermediate

// async global->LDS, 16B per lane, wave-uniform LDS base (m97/m193 pattern)
#define GLOAD_LDS(g, l) __builtin_amdgcn_global_load_lds( \
    (const __attribute__((address_space(1))) unsigned int*)(const void*)(g), \
    (__attribute__((address_space(3))) unsigned int*)(void*)(l), 16, 0, 0)

DI unsigned short f2bf(float f) {
  unsigned u = __float_as_uint(f);
  u = (u + 0x7fffu + ((u >> 16) & 1u)) >> 16;   // round-to-nearest-even
  return (unsigned short)u;
}
DI float bf2f(unsigned short b) { return __uint_as_float(((unsigned)b) << 16); }

// ---------------- gate (fp64 ranking; gw staged in LDS) -- round-9-verified ----------------
// Round-17: counts atomics removed (route_kernel derives counts from topk_idx).
__global__ __launch_bounds__(256) void gate_kernel(
    const float* __restrict__ x, const float* __restrict__ gw,
    const float* __restrict__ gb, int* __restrict__ topk_idx,
    float* __restrict__ topk_w) {
  __shared__ float gwl[16 * 1028];          // 65792 B
  const int tid = threadIdx.x;
#pragma unroll
  for (int it = 0; it < 16; ++it) {
    int i4 = it * 256 + tid;                // float4 index in [0,4096)
    int row = i4 >> 8, col4 = i4 & 255;
    float4 v = ((const float4*)gw)[i4];
    *(float4*)(gwl + row * 1028 + col4 * 4) = v;
  }
  __syncthreads();

  const int lane = tid & 63;
  const int n = blockIdx.x * 4 + (tid >> 6);
  const int e = lane & 15;          // expert
  const int c = lane >> 4;          // chunk [0,4)
  const int g = e >> 2;             // group [0,4)

  const float4* x4 = (const float4*)(x + (size_t)n * HID + c * 256);
  const float4* w4 = (const float4*)(gwl + e * 1028 + c * 256);

  double acc0 = 0, acc1 = 0, acc2 = 0, acc3 = 0, acc4 = 0, acc5 = 0, acc6 = 0, acc7 = 0;
#pragma unroll
  for (int i = 0; i < 32; ++i) {
    float4 xa = x4[2 * i], xb = x4[2 * i + 1];
    float4 wa = w4[2 * i], wb = w4[2 * i + 1];
    acc0 += (double)xa.x * wa.x; acc1 += (double)xa.y * wa.y;
    acc2 += (double)xa.z * wa.z; acc3 += (double)xa.w * wa.w;
    acc4 += (double)xb.x * wb.x; acc5 += (double)xb.y * wb.y;
    acc6 += (double)xb.z * wb.z; acc7 += (double)xb.w * wb.w;
  }
  double L = ((acc0 + acc1) + (acc2 + acc3)) + ((acc4 + acc5) + (acc6 + acc7));
  L += __shfl_xor(L, 16);
  L += __shfl_xor(L, 32);

  double sig = 1.0 / (1.0 + exp(-L));
  double sfc = sig + (double)gb[e];

  double o1 = __shfl_xor(sfc, 1);
  double hi = fmax(sfc, o1), lo = fmin(sfc, o1);
  double hi2 = __shfl_xor(hi, 2), lo2 = __shfl_xor(lo, 2);
  double gs = fmax(hi, hi2) + fmax(fmin(hi, hi2), fmax(lo, lo2));

  double gsA = __shfl_xor(gs, 4);
  double gsB = __shfl_xor(gs, 8);
  double gsC = __shfl_xor(gs, 12);
  int grank = 0;
  grank += (gsA > gs || (gsA == gs && (g ^ 1) < g)) ? 1 : 0;
  grank += (gsB > gs || (gsB == gs && (g ^ 2) < g)) ? 1 : 0;
  grank += (gsC > gs || (gsC == gs && (g ^ 3) < g)) ? 1 : 0;
  const bool allowed = grank < 2;

  double sv = allowed ? sfc : -1e300;
  int rank = 0;
#pragma unroll
  for (int m = 1; m < 16; ++m) {
    double o = __shfl_xor(sv, m);
    int oe = e ^ m;
    rank += (o > sv || (o == sv && oe < e)) ? 1 : 0;
  }
  const bool chosen = allowed && (rank < 4);

  double t = chosen ? sig : 0.0;
  t += __shfl_xor(t, 1);
  t += __shfl_xor(t, 2);
  t += __shfl_xor(t, 4);
  t += __shfl_xor(t, 8);

  if (chosen && c == 0) {
    topk_idx[n * 4 + rank] = e;
    topk_w[n * 4 + rank] = (float)(sig / (t + 1e-20) * 2.5);
  }
}

// ---------------- fused routing: counts + prefix + scatter, one block ----------------
// Round-17: replaces init_counts + prefix_kernel + scatter_kernel (saves 2 launch
// gaps + their exec). Single block, 1024 threads, LDS counts/cursor. ~16K LDS
// atomics/pass over 16 banks ~ few us.
__global__ __launch_bounds__(1024) void route_kernel(
    const int* __restrict__ topk_idx,
    int* __restrict__ counts, int* __restrict__ offsets,
    int* __restrict__ perm, int* __restrict__ pos) {
  __shared__ int lc[16], lo[16];
  const int tid = threadIdx.x;
  if (tid < 16) lc[tid] = 0;
  __syncthreads();
  int ecache[16];
#pragma unroll
  for (int j = 0; j < 16; ++j) {
    int i = tid + j * 1024;
    ecache[j] = topk_idx[i];
    atomicAdd(&lc[ecache[j]], 1);
  }
  __syncthreads();
  if (tid == 0) {
    int s = 0;
    for (int k = 0; k < NEXP; ++k) {
      lo[k] = s; offsets[k] = s; counts[k] = lc[k]; s += lc[k];
    }
    offsets[NEXP] = s;
  }
  __syncthreads();
  if (tid < 16) lc[tid] = lo[tid];   // reuse lc as cursor
  __syncthreads();
#pragma unroll
  for (int j = 0; j < 16; ++j) {
    int i = tid + j * 1024;
    int slot = atomicAdd(&lc[ecache[j]], 1);
    perm[slot] = i >> 2;
    pos[i] = slot;
  }
}

// ---------------- fp32 -> bf16 convert (all arrays incl. x, one launch) ----------------
__global__ __launch_bounds__(256) void convert_all(
    const float* __restrict__ x, const float* __restrict__ wg,
    const float* __restrict__ wu, const float* __restrict__ wd,
    const float* __restrict__ sg, const float* __restrict__ su,
    const float* __restrict__ sd,
    unsigned short* __restrict__ xb, unsigned short* __restrict__ wgb,
    unsigned short* __restrict__ wub, unsigned short* __restrict__ wdb,
    unsigned short* __restrict__ sgb, unsigned short* __restrict__ sub,
    unsigned short* __restrict__ sdb) {
  long g = (long)blockIdx.x * 256 + threadIdx.x;   // float4 index, total 8126464
  const float* s; unsigned short* d; long o;
  if      (g < 1048576L) { s = x;  d = xb;  o = g; }
  else if (g < 3145728L) { s = wg; d = wgb; o = g - 1048576L; }
  else if (g < 5242880L) { s = wu; d = wub; o = g - 3145728L; }
  else if (g < 7340032L) { s = wd; d = wdb; o = g - 5242880L; }
  else if (g < 7602176L) { s = sg; d = sgb; o = g - 7340032L; }
  else if (g < 7864320L) { s = su; d = sub; o = g - 7602176L; }
  else                   { s = sd; d = sdb; o = g - 7864320L; }
  float4 v = ((const float4*)s)[o];
  ushort4 r;
  r.x = f2bf(v.x); r.y = f2bf(v.y); r.z = f2bf(v.z); r.w = f2bf(v.w);
  ((ushort4*)d)[o] = r;
}

// ---------------- merged bf16 MFMA GEMM level: routed job + shared job ----------------
// K-loop: round-13 depth-2 counted-vmcnt form VERBATIM (best measured 73.6/73.7us;
// rounds 10/11/14 schedule variants all neutral/negative -- 2-phase plateau;
// rounds 15/16 convert-overlap variants negative -- blocks monopolize CU slots).
// GU: BM=256, BN=128x2 (g,u). Down: BN=256. Both: BUFB=32 KB, 4 DMA
// loads/wave/stage -> vmcnt(4) steady / 0 tail. XOR k-swizzle conflict-free.
template <bool GU>
__global__ __launch_bounds__(512) void gemm_lvl(
    // routed job
    const unsigned short* __restrict__ Ar, const unsigned short* __restrict__ B0r,
    const unsigned short* __restrict__ B1r, unsigned short* __restrict__ Cr,
    int Kr, int ldcr, long eStrideB,
    const int* __restrict__ counts, const int* __restrict__ offsets,
    const int* __restrict__ perm, int useGather,
    // shared job
    const unsigned short* __restrict__ As, const unsigned short* __restrict__ B0s,
    const unsigned short* __restrict__ B1s, void* __restrict__ Cs,
    int Ms, int Ks, int ldcs, int nShared) {
  const int bx = blockIdx.x;
  const bool isShared = bx < nShared;
  int mt, y, cnt, off = 0, K, ldc;
  const unsigned short *A, *Bg, *Bu = nullptr;
  bool gather = false;
  if (isShared) {
    mt = bx & 15; y = bx >> 4;              // 16 mtiles(256) x ny
    cnt = Ms; K = Ks; ldc = ldcs;
    A = As; Bg = B0s;
    if constexpr (GU) Bu = B1s;
  } else {
    int r = bx - nShared;
    int e = ((r & 7) << 1) | ((r >> 3) & 1); // XCD (r&7) owns experts {2c,2c+1}
    mt = (r >> 4) & 15; y = r >> 8;
    cnt = counts[e]; off = offsets[e];
    if (mt * 256 >= cnt) return;
    K = Kr; ldc = ldcr;
    A = Ar; Bg = B0r + (long)e * eStrideB;
    if constexpr (GU) Bu = B1r + (long)e * eStrideB;
    gather = (useGather != 0);
  }
  const int n0 = y * (GU ? 128 : 256);

  const int tid = threadIdx.x;
  const int lane = tid & 63;
  const int wid = tid >> 6;                  // [0,8)
  const int wm = (wid >> 1) * 64;
  const int wn = (wid & 1) * (GU ? 64 : 128);

  constexpr int NI = GU ? 4 : 8;             // per-wave N fragments
  constexpr int ABYTES = 16384;              // A region: 256 rows x 32 shorts
  constexpr int BBYTES = GU ? 8192 : 16384;  // per B matrix region
  constexpr int BUFB = 32768;                // A + (g,u | B) = 32 KB both levels
  __shared__ __align__(16) unsigned char lds[2 * 32768];

  // ---- staging geometry (conflict-free both sides; rounds 6-16) ----
  // lane l of instr i: c = i*64+l, row = c>>2, kc = (c&3) ^ ((row>>1)&3).
  const unsigned short* aP[2]; int aD[2];
#pragma unroll
  for (int j = 0; j < 2; ++j) {
    int c = (wid * 2 + j) * 64 + lane;
    int row = c >> 2;
    int kc = (c & 3) ^ ((row >> 1) & 3);
    aD[j] = (wid * 2 + j) * 1024;
    int am = mt * 256 + row;
    int amc = am < cnt ? am : cnt - 1;
    long ar;
    if (isShared)    ar = amc;
    else if (gather) ar = perm[off + amc];
    else             ar = off + amc;
    aP[j] = A + ar * (long)K + kc * 8;
  }
  const unsigned short* gP[2]; const unsigned short* uP = nullptr;
  int bDj[2];
  if constexpr (GU) {
    int c = wid * 64 + lane;
    int row = c >> 2;                        // [0,128)
    int kc = (c & 3) ^ ((row >> 1) & 3);
    bDj[0] = wid * 1024;
    gP[0] = Bg + (long)(n0 + row) * K + kc * 8;
    uP    = Bu + (long)(n0 + row) * K + kc * 8;
  } else {
#pragma unroll
    for (int j = 0; j < 2; ++j) {
      int c = (wid * 2 + j) * 64 + lane;
      int row = c >> 2;                      // [0,256)
      int kc = (c & 3) ^ ((row >> 1) & 3);
      bDj[j] = (wid * 2 + j) * 1024;
      gP[j] = Bg + (long)(n0 + row) * K + kc * 8;
    }
  }

  auto STAGE = [&](int buf, int t) {
    unsigned char* base = lds + buf * BUFB;
    const int koff = t * 32;                 // shorts
    GLOAD_LDS(aP[0] + koff, base + aD[0]);
    GLOAD_LDS(aP[1] + koff, base + aD[1]);
    if constexpr (GU) {
      GLOAD_LDS(gP[0] + koff, base + ABYTES + bDj[0]);
      GLOAD_LDS(uP + koff, base + ABYTES + BBYTES + bDj[0]);
    } else {
      GLOAD_LDS(gP[0] + koff, base + ABYTES + bDj[0]);
      GLOAD_LDS(gP[1] + koff, base + ABYTES + bDj[1]);
    }
  };

  f32x4 accg[4][NI];
  f32x4 accu[GU ? 4 : 1][GU ? 4 : 1];
#pragma unroll
  for (int a = 0; a < 4; ++a) {
#pragma unroll
    for (int b = 0; b < NI; ++b) accg[a][b] = f32x4{0.f, 0.f, 0.f, 0.f};
    if constexpr (GU) {
#pragma unroll
      for (int b = 0; b < 4; ++b) accu[a][b] = f32x4{0.f, 0.f, 0.f, 0.f};
    }
  }

  const int r16 = lane & 15, kc4 = lane >> 4;
  const int kq = (kc4 ^ ((r16 >> 1) & 3)) * 8;   // swizzled k-chunk (shorts)
  auto COMPUTE = [&](int buf) {
    const unsigned short* bA = (const unsigned short*)(lds + buf * BUFB);
    const unsigned short* bG = bA + ABYTES / 2;
    const unsigned short* bU = bG + BBYTES / 2;   // GU only
    bf16x8 af[4], fr[NI], uf[4];
#pragma unroll
    for (int mi = 0; mi < 4; ++mi)
      af[mi] = *(const bf16x8*)(bA + (wm + mi * 16 + r16) * 32 + kq);
#pragma unroll
    for (int ni = 0; ni < NI; ++ni)
      fr[ni] = *(const bf16x8*)(bG + (wn + ni * 16 + r16) * 32 + kq);
    if constexpr (GU) {
#pragma unroll
      for (int ni = 0; ni < 4; ++ni)
        uf[ni] = *(const bf16x8*)(bU + (wn + ni * 16 + r16) * 32 + kq);
    }
#pragma unroll
    for (int mi = 0; mi < 4; ++mi)
#pragma unroll
      for (int ni = 0; ni < NI; ++ni) {
        accg[mi][ni] = __builtin_amdgcn_mfma_f32_16x16x32_bf16(af[mi], fr[ni], accg[mi][ni], 0, 0, 0);
        if constexpr (GU)
          accu[mi][ni] = __builtin_amdgcn_mfma_f32_16x16x32_bf16(af[mi], uf[ni], accu[mi][ni], 0, 0, 0);
      }
  };

  // ---- depth-2 pipeline, counted vmcnt (4 loads/wave/stage both levels) ----
  const int NT = K >> 5;
  STAGE(0, 0);
  STAGE(1, 1);
  int cur = 0;
  for (int t = 0; t < NT; ++t) {
    if (t + 1 < NT) asm volatile("s_waitcnt vmcnt(4)" ::: "memory");
    else            asm volatile("s_waitcnt vmcnt(0)" ::: "memory");
    __builtin_amdgcn_s_barrier();        // all waves' tile-t loads now visible
    COMPUTE(cur);
    __builtin_amdgcn_s_barrier();        // all waves done reading buf cur
    if (t + 2 < NT) STAGE(cur, t + 2);   // refill freed buffer
    cur ^= 1;
  }

  // epilogue: C layout col=lane&15, row=(lane>>4)*4+reg  [m89-verified]
#pragma unroll
  for (int mi = 0; mi < 4; ++mi)
#pragma unroll
    for (int ni = 0; ni < NI; ++ni)
#pragma unroll
      for (int j = 0; j < 4; ++j) {
        int r = wm + mi * 16 + kc4 * 4 + j;
        int gr = mt * 256 + r;
        if (gr < cnt) {
          int c = n0 + wn + ni * 16 + r16;
          if constexpr (GU) {
            float g = accg[mi][ni][j], u = accu[mi][ni][j];
            float sg = g / (1.f + __expf(-g));       // silu
            unsigned short v = f2bf(sg * u);
            if (isShared) ((unsigned short*)Cs)[(long)gr * ldc + c] = v;
            else          Cr[((long)off + gr) * ldc + c] = v;
          } else {
            if (isShared) ((float*)Cs)[(long)gr * ldc + c] = accg[mi][ni][j];
            else          Cr[((long)off + gr) * ldc + c] = f2bf(accg[mi][ni][j]);
          }
        }
      }
}

// ---------------- final combine: out = x + shared(in d_out) + sum_k w_k*yout ----------------
__global__ __launch_bounds__(256) void combine_kernel(
    const float* __restrict__ x, const float* __restrict__ sh,
    const unsigned short* __restrict__ yout, const float* __restrict__ tw,
    const int* __restrict__ pos, float* __restrict__ out) {
  int n = blockIdx.x;                  // one block per token
  int h4 = threadIdx.x << 2;           // 256 threads * 4 floats = 1024
  float4 xv = *(const float4*)(x + (long)n * HID + h4);
  float4 sv = *(const float4*)(sh + (long)n * HID + h4);   // shared-expert result (read before write)
  float a0 = xv.x + sv.x, a1 = xv.y + sv.y, a2 = xv.z + sv.z, a3 = xv.w + sv.w;
#pragma unroll
  for (int k = 0; k < 4; ++k) {
    float w = tw[n * 4 + k];
    long slot = pos[n * 4 + k];
    ushort4 yv = *(const ushort4*)(yout + slot * HID + h4);
    a0 += w * bf2f(yv.x); a1 += w * bf2f(yv.y);
    a2 += w * bf2f(yv.z); a3 += w * bf2f(yv.w);
  }
  float4 o; o.x = a0; o.y = a1; o.z = a2; o.w = a3;
  *(float4*)(out + (long)n * HID + h4) = o;
}

// ---------------- launch ----------------
extern "C" void kernel_launch(void* const* d_in, const int* in_sizes, int n_in,
                              void* d_out, int out_size, void* d_ws, size_t ws_size,
                              hipStream_t stream) {
  (void)in_sizes; (void)n_in; (void)out_size; (void)ws_size;
  const float* x   = (const float*)d_in[0];
  const float* gw  = (const float*)d_in[1];
  const float* gb  = (const float*)d_in[2];
  const float* Wg  = (const float*)d_in[3];
  const float* Wu  = (const float*)d_in[4];
  const float* Wd  = (const float*)d_in[5];
  const float* Wsg = (const float*)d_in[6];
  const float* Wsu = (const float*)d_in[7];
  const float* Wsd = (const float*)d_in[8];
  float* out = (float*)d_out;

  // ---- workspace layout (big buffers start at 512 KiB; small region ends 262400) ----
  char* w = (char*)d_ws;
  int*   counts   = (int*)(w + 0);                    // 64 B
  int*   offsets  = (int*)(w + 128);                  // 128 B (17 ints)
  int*   topk_idx = (int*)(w + 256);                  // 65536 B
  float* topk_w   = (float*)(w + 256 + 65536);        // 65536 B
  int*   perm     = (int*)(w + 256 + 131072);         // 65536 B
  int*   pos      = (int*)(w + 256 + 196608);         // 65536 B
  size_t o = 524288;                                  // big buffers from 512 KiB
  unsigned short* xb   = (unsigned short*)(w + o); o += (size_t)NTOK * HID * 2;       // 8 MB
  unsigned short* WgB  = (unsigned short*)(w + o); o += (size_t)NEXP * IMO * HID * 2; // 16 MB
  unsigned short* WuB  = (unsigned short*)(w + o); o += (size_t)NEXP * IMO * HID * 2; // 16 MB
  unsigned short* WdB  = (unsigned short*)(w + o); o += (size_t)NEXP * HID * IMO * 2; // 16 MB
  unsigned short* WsgB = (unsigned short*)(w + o); o += (size_t)SHI * HID * 2;        // 2 MB
  unsigned short* WsuB = (unsigned short*)(w + o); o += (size_t)SHI * HID * 2;        // 2 MB
  unsigned short* WsdB = (unsigned short*)(w + o); o += (size_t)HID * SHI * 2;        // 2 MB
  unsigned short* act  = (unsigned short*)(w + o); o += (size_t)NTOK * 4 * IMO * 2;   // 16 MB
  unsigned short* yout = (unsigned short*)(w + o); o += (size_t)NTOK * 4 * HID * 2;   // 32 MB
  unsigned short* sact = (unsigned short*)(w + o); o += (size_t)NTOK * SHI * 2;       // 8 MB
  // total ws use ~118.5 MiB; shared-expert fp32 output goes directly to d_out

  gate_kernel<<<NTOK / 4, 256, 0, stream>>>(x, gw, gb, topk_idx, topk_w);
  route_kernel<<<1, 1024, 0, stream>>>(topk_idx, counts, offsets, perm, pos);
  convert_all<<<31744, 256, 0, stream>>>(x, Wg, Wu, Wd, Wsg, Wsu, Wsd,
                                         xb, WgB, WuB, WdB, WsgB, WsuB, WsdB);
  // Level 1: shared gate+up (128 blocks: 16 mt x 8 y) + routed gate+up
  // (1024 slots: e,mt 256 x ny 4), BN=128 per matrix, 512 threads/block.
  gemm_lvl<true><<<128 + 1024, 512, 0, stream>>>(
      xb, WgB, WuB, act, HID, IMO, (long)IMO * HID, counts, offsets, perm, 1,
      xb, WsgB, WsuB, sact, NTOK, HID, SHI, 128);
  // Level 2: shared down (64 blocks: 16 mt x 4 y) + routed down
  // (1024 slots: e,mt 256 x ny 4), BN=256.
  gemm_lvl<false><<<64 + 1024, 512, 0, stream>>>(
      act, WdB, nullptr, yout, IMO, HID, (long)HID * IMO, counts, offsets, nullptr, 0,
      sact, WsdB, nullptr, out, NTOK, SHI, HID, 64);
  // out = x + shared + sum_k w_k * yout[pos]
  combine_kernel<<<NTOK, 256, 0, stream>>>(x, out, yout, topk_w, pos, out);
}

// Round 18
// 186.851 us; speedup vs baseline: 1.4718x; 1.0112x over previous
//
#include <hip/hip_runtime.h>
#include <cstdint>

typedef __bf16 bf16x8 __attribute__((ext_vector_type(8)));
typedef float f32x4 __attribute__((ext_vector_type(4)));

#define DI __device__ __forceinline__

constexpr int NTOK = 4096;   // B*S
constexpr int HID  = 1024;
constexpr int IMO  = 512;    // moe intermediate
constexpr int NEXP = 16;
constexpr int SHI  = 1024;   // shared intermediate

// async global->LDS, 16B per lane, wave-uniform LDS base (m97/m193 pattern)
#define GLOAD_LDS(g, l) __builtin_amdgcn_global_load_lds( \
    (const __attribute__((address_space(1))) unsigned int*)(const void*)(g), \
    (__attribute__((address_space(3))) unsigned int*)(void*)(l), 16, 0, 0)

DI unsigned short f2bf(float f) {
  unsigned u = __float_as_uint(f);
  u = (u + 0x7fffu + ((u >> 16) & 1u)) >> 16;   // round-to-nearest-even
  return (unsigned short)u;
}
DI float bf2f(unsigned short b) { return __uint_as_float(((unsigned)b) << 16); }

// ---------------- gate (fp64 ranking; gw staged in LDS; NO global atomics) ----------------
// Round-17 lesson: 16K atomicAdds on 16 words cost ~60us (cross-XCD contention).
__global__ __launch_bounds__(256) void gate_kernel(
    const float* __restrict__ x, const float* __restrict__ gw,
    const float* __restrict__ gb, int* __restrict__ topk_idx,
    float* __restrict__ topk_w) {
  __shared__ float gwl[16 * 1028];          // 65792 B
  const int tid = threadIdx.x;
#pragma unroll
  for (int it = 0; it < 16; ++it) {
    int i4 = it * 256 + tid;                // float4 index in [0,4096)
    int row = i4 >> 8, col4 = i4 & 255;
    float4 v = ((const float4*)gw)[i4];
    *(float4*)(gwl + row * 1028 + col4 * 4) = v;
  }
  __syncthreads();

  const int lane = tid & 63;
  const int n = blockIdx.x * 4 + (tid >> 6);
  const int e = lane & 15;          // expert
  const int c = lane >> 4;          // chunk [0,4)
  const int g = e >> 2;             // group [0,4)

  const float4* x4 = (const float4*)(x + (size_t)n * HID + c * 256);
  const float4* w4 = (const float4*)(gwl + e * 1028 + c * 256);

  double acc0 = 0, acc1 = 0, acc2 = 0, acc3 = 0, acc4 = 0, acc5 = 0, acc6 = 0, acc7 = 0;
#pragma unroll
  for (int i = 0; i < 32; ++i) {
    float4 xa = x4[2 * i], xb = x4[2 * i + 1];
    float4 wa = w4[2 * i], wb = w4[2 * i + 1];
    acc0 += (double)xa.x * wa.x; acc1 += (double)xa.y * wa.y;
    acc2 += (double)xa.z * wa.z; acc3 += (double)xa.w * wa.w;
    acc4 += (double)xb.x * wb.x; acc5 += (double)xb.y * wb.y;
    acc6 += (double)xb.z * wb.z; acc7 += (double)xb.w * wb.w;
  }
  double L = ((acc0 + acc1) + (acc2 + acc3)) + ((acc4 + acc5) + (acc6 + acc7));
  L += __shfl_xor(L, 16);
  L += __shfl_xor(L, 32);

  double sig = 1.0 / (1.0 + exp(-L));
  double sfc = sig + (double)gb[e];

  double o1 = __shfl_xor(sfc, 1);
  double hi = fmax(sfc, o1), lo = fmin(sfc, o1);
  double hi2 = __shfl_xor(hi, 2), lo2 = __shfl_xor(lo, 2);
  double gs = fmax(hi, hi2) + fmax(fmin(hi, hi2), fmax(lo, lo2));

  double gsA = __shfl_xor(gs, 4);
  double gsB = __shfl_xor(gs, 8);
  double gsC = __shfl_xor(gs, 12);
  int grank = 0;
  grank += (gsA > gs || (gsA == gs && (g ^ 1) < g)) ? 1 : 0;
  grank += (gsB > gs || (gsB == gs && (g ^ 2) < g)) ? 1 : 0;
  grank += (gsC > gs || (gsC == gs && (g ^ 3) < g)) ? 1 : 0;
  const bool allowed = grank < 2;

  double sv = allowed ? sfc : -1e300;
  int rank = 0;
#pragma unroll
  for (int m = 1; m < 16; ++m) {
    double o = __shfl_xor(sv, m);
    int oe = e ^ m;
    rank += (o > sv || (o == sv && oe < e)) ? 1 : 0;
  }
  const bool chosen = allowed && (rank < 4);

  double t = chosen ? sig : 0.0;
  t += __shfl_xor(t, 1);
  t += __shfl_xor(t, 2);
  t += __shfl_xor(t, 4);
  t += __shfl_xor(t, 8);

  if (chosen && c == 0) {
    topk_idx[n * 4 + rank] = e;
    topk_w[n * 4 + rank] = (float)(sig / (t + 1e-20) * 2.5);
  }
}

// ---------------- fused routing: counts + prefix + scatter, one block ----------------
__global__ __launch_bounds__(1024) void route_kernel(
    const int* __restrict__ topk_idx,
    int* __restrict__ counts, int* __restrict__ offsets,
    int* __restrict__ perm, int* __restrict__ pos) {
  __shared__ int lc[16], lo[16];
  const int tid = threadIdx.x;
  if (tid < 16) lc[tid] = 0;
  __syncthreads();
  int ecache[16];
#pragma unroll
  for (int j = 0; j < 16; ++j) {
    int i = tid + j * 1024;
    ecache[j] = topk_idx[i];
    atomicAdd(&lc[ecache[j]], 1);
  }
  __syncthreads();
  if (tid == 0) {
    int s = 0;
    for (int k = 0; k < NEXP; ++k) {
      lo[k] = s; offsets[k] = s; counts[k] = lc[k]; s += lc[k];
    }
    offsets[NEXP] = s;
  }
  __syncthreads();
  if (tid < 16) lc[tid] = lo[tid];   // reuse lc as cursor
  __syncthreads();
#pragma unroll
  for (int j = 0; j < 16; ++j) {
    int i = tid + j * 1024;
    int slot = atomicAdd(&lc[ecache[j]], 1);
    perm[slot] = i >> 2;
    pos[i] = slot;
  }
}

// ---------------- fp32 -> bf16 convert (all arrays incl. x, one launch) ----------------
__global__ __launch_bounds__(256) void convert_all(
    const float* __restrict__ x, const float* __restrict__ wg,
    const float* __restrict__ wu, const float* __restrict__ wd,
    const float* __restrict__ sg, const float* __restrict__ su,
    const float* __restrict__ sd,
    unsigned short* __restrict__ xb, unsigned short* __restrict__ wgb,
    unsigned short* __restrict__ wub, unsigned short* __restrict__ wdb,
    unsigned short* __restrict__ sgb, unsigned short* __restrict__ sub,
    unsigned short* __restrict__ sdb) {
  long g = (long)blockIdx.x * 256 + threadIdx.x;   // float4 index, total 8126464
  const float* s; unsigned short* d; long o;
  if      (g < 1048576L) { s = x;  d = xb;  o = g; }
  else if (g < 3145728L) { s = wg; d = wgb; o = g - 1048576L; }
  else if (g < 5242880L) { s = wu; d = wub; o = g - 3145728L; }
  else if (g < 7340032L) { s = wd; d = wdb; o = g - 5242880L; }
  else if (g < 7602176L) { s = sg; d = sgb; o = g - 7340032L; }
  else if (g < 7864320L) { s = su; d = sub; o = g - 7602176L; }
  else                   { s = sd; d = sdb; o = g - 7864320L; }
  float4 v = ((const float4*)s)[o];
  ushort4 r;
  r.x = f2bf(v.x); r.y = f2bf(v.y); r.z = f2bf(v.z); r.w = f2bf(v.w);
  ((ushort4*)d)[o] = r;
}

// ---------------- merged bf16 MFMA GEMM level: routed job + shared job ----------------
// Round-18: pure depth-3 prefetch (3 buffers, 96 KB LDS; steady vmcnt(8) -> 4 -> 0)
// on the round-13 loop. Isolates the one variable round-11 bundled with the
// harmful phase-split/setprio (its STAGE/vmcnt pattern ran correctly there).
// Depth-2 gave loads only ~1 K-step (~1150cy) to cover ~900cy HBM latency.
// GU: BM=256, BN=128x2 (g,u). Down: BN=256. XOR k-swizzle conflict-free.
template <bool GU>
__global__ __launch_bounds__(512) void gemm_lvl(
    // routed job
    const unsigned short* __restrict__ Ar, const unsigned short* __restrict__ B0r,
    const unsigned short* __restrict__ B1r, unsigned short* __restrict__ Cr,
    int Kr, int ldcr, long eStrideB,
    const int* __restrict__ counts, const int* __restrict__ offsets,
    const int* __restrict__ perm, int useGather,
    // shared job
    const unsigned short* __restrict__ As, const unsigned short* __restrict__ B0s,
    const unsigned short* __restrict__ B1s, void* __restrict__ Cs,
    int Ms, int Ks, int ldcs, int nShared) {
  const int bx = blockIdx.x;
  const bool isShared = bx < nShared;
  int mt, y, cnt, off = 0, K, ldc;
  const unsigned short *A, *Bg, *Bu = nullptr;
  bool gather = false;
  if (isShared) {
    mt = bx & 15; y = bx >> 4;              // 16 mtiles(256) x ny
    cnt = Ms; K = Ks; ldc = ldcs;
    A = As; Bg = B0s;
    if constexpr (GU) Bu = B1s;
  } else {
    int r = bx - nShared;
    int e = ((r & 7) << 1) | ((r >> 3) & 1); // XCD (r&7) owns experts {2c,2c+1}
    mt = (r >> 4) & 15; y = r >> 8;
    cnt = counts[e]; off = offsets[e];
    if (mt * 256 >= cnt) return;
    K = Kr; ldc = ldcr;
    A = Ar; Bg = B0r + (long)e * eStrideB;
    if constexpr (GU) Bu = B1r + (long)e * eStrideB;
    gather = (useGather != 0);
  }
  const int n0 = y * (GU ? 128 : 256);

  const int tid = threadIdx.x;
  const int lane = tid & 63;
  const int wid = tid >> 6;                  // [0,8)
  const int wm = (wid >> 1) * 64;
  const int wn = (wid & 1) * (GU ? 64 : 128);

  constexpr int NI = GU ? 4 : 8;             // per-wave N fragments
  constexpr int ABYTES = 16384;              // A region: 256 rows x 32 shorts
  constexpr int BBYTES = GU ? 8192 : 16384;  // per B matrix region
  constexpr int BUFB = 32768;                // A + (g,u | B) = 32 KB both levels
  __shared__ __align__(16) unsigned char lds[3 * 32768];   // depth-3

  // ---- staging geometry (conflict-free both sides; rounds 6-17) ----
  // lane l of instr i: c = i*64+l, row = c>>2, kc = (c&3) ^ ((row>>1)&3).
  const unsigned short* aP[2]; int aD[2];
#pragma unroll
  for (int j = 0; j < 2; ++j) {
    int c = (wid * 2 + j) * 64 + lane;
    int row = c >> 2;
    int kc = (c & 3) ^ ((row >> 1) & 3);
    aD[j] = (wid * 2 + j) * 1024;
    int am = mt * 256 + row;
    int amc = am < cnt ? am : cnt - 1;
    long ar;
    if (isShared)    ar = amc;
    else if (gather) ar = perm[off + amc];
    else             ar = off + amc;
    aP[j] = A + ar * (long)K + kc * 8;
  }
  const unsigned short* gP[2]; const unsigned short* uP = nullptr;
  int bDj[2];
  if constexpr (GU) {
    int c = wid * 64 + lane;
    int row = c >> 2;                        // [0,128)
    int kc = (c & 3) ^ ((row >> 1) & 3);
    bDj[0] = wid * 1024;
    gP[0] = Bg + (long)(n0 + row) * K + kc * 8;
    uP    = Bu + (long)(n0 + row) * K + kc * 8;
  } else {
#pragma unroll
    for (int j = 0; j < 2; ++j) {
      int c = (wid * 2 + j) * 64 + lane;
      int row = c >> 2;                      // [0,256)
      int kc = (c & 3) ^ ((row >> 1) & 3);
      bDj[j] = (wid * 2 + j) * 1024;
      gP[j] = Bg + (long)(n0 + row) * K + kc * 8;
    }
  }

  auto STAGE = [&](int buf, int t) {
    unsigned char* base = lds + buf * BUFB;
    const int koff = t * 32;                 // shorts
    GLOAD_LDS(aP[0] + koff, base + aD[0]);
    GLOAD_LDS(aP[1] + koff, base + aD[1]);
    if constexpr (GU) {
      GLOAD_LDS(gP[0] + koff, base + ABYTES + bDj[0]);
      GLOAD_LDS(uP + koff, base + ABYTES + BBYTES + bDj[0]);
    } else {
      GLOAD_LDS(gP[0] + koff, base + ABYTES + bDj[0]);
      GLOAD_LDS(gP[1] + koff, base + ABYTES + bDj[1]);
    }
  };

  f32x4 accg[4][NI];
  f32x4 accu[GU ? 4 : 1][GU ? 4 : 1];
#pragma unroll
  for (int a = 0; a < 4; ++a) {
#pragma unroll
    for (int b = 0; b < NI; ++b) accg[a][b] = f32x4{0.f, 0.f, 0.f, 0.f};
    if constexpr (GU) {
#pragma unroll
      for (int b = 0; b < 4; ++b) accu[a][b] = f32x4{0.f, 0.f, 0.f, 0.f};
    }
  }

  const int r16 = lane & 15, kc4 = lane >> 4;
  const int kq = (kc4 ^ ((r16 >> 1) & 3)) * 8;   // swizzled k-chunk (shorts)
  auto COMPUTE = [&](int buf) {
    const unsigned short* bA = (const unsigned short*)(lds + buf * BUFB);
    const unsigned short* bG = bA + ABYTES / 2;
    const unsigned short* bU = bG + BBYTES / 2;   // GU only
    bf16x8 af[4], fr[NI], uf[4];
#pragma unroll
    for (int mi = 0; mi < 4; ++mi)
      af[mi] = *(const bf16x8*)(bA + (wm + mi * 16 + r16) * 32 + kq);
#pragma unroll
    for (int ni = 0; ni < NI; ++ni)
      fr[ni] = *(const bf16x8*)(bG + (wn + ni * 16 + r16) * 32 + kq);
    if constexpr (GU) {
#pragma unroll
      for (int ni = 0; ni < 4; ++ni)
        uf[ni] = *(const bf16x8*)(bU + (wn + ni * 16 + r16) * 32 + kq);
    }
#pragma unroll
    for (int mi = 0; mi < 4; ++mi)
#pragma unroll
      for (int ni = 0; ni < NI; ++ni) {
        accg[mi][ni] = __builtin_amdgcn_mfma_f32_16x16x32_bf16(af[mi], fr[ni], accg[mi][ni], 0, 0, 0);
        if constexpr (GU)
          accu[mi][ni] = __builtin_amdgcn_mfma_f32_16x16x32_bf16(af[mi], uf[ni], accu[mi][ni], 0, 0, 0);
      }
  };

  // ---- depth-3 pipeline, counted vmcnt (4 loads/wave/stage both levels) ----
  const int NT = K >> 5;                 // >= 16
  STAGE(0, 0);
  STAGE(1, 1);
  STAGE(2, 2);
  int cur = 0;
  for (int t = 0; t < NT; ++t) {
    if (t + 2 < NT)      asm volatile("s_waitcnt vmcnt(8)" ::: "memory");
    else if (t + 1 < NT) asm volatile("s_waitcnt vmcnt(4)" ::: "memory");
    else                 asm volatile("s_waitcnt vmcnt(0)" ::: "memory");
    __builtin_amdgcn_s_barrier();        // tile t visible to all waves
    COMPUTE(cur);
    __builtin_amdgcn_s_barrier();        // all waves done reading buf cur
    if (t + 3 < NT) STAGE(cur, t + 3);   // refill freed buffer (cur == (t+3)%3)
    cur = (cur == 2) ? 0 : cur + 1;
  }

  // epilogue: C layout col=lane&15, row=(lane>>4)*4+reg  [m89-verified]
#pragma unroll
  for (int mi = 0; mi < 4; ++mi)
#pragma unroll
    for (int ni = 0; ni < NI; ++ni)
#pragma unroll
      for (int j = 0; j < 4; ++j) {
        int r = wm + mi * 16 + kc4 * 4 + j;
        int gr = mt * 256 + r;
        if (gr < cnt) {
          int c = n0 + wn + ni * 16 + r16;
          if constexpr (GU) {
            float g = accg[mi][ni][j], u = accu[mi][ni][j];
            float sg = g / (1.f + __expf(-g));       // silu
            unsigned short v = f2bf(sg * u);
            if (isShared) ((unsigned short*)Cs)[(long)gr * ldc + c] = v;
            else          Cr[((long)off + gr) * ldc + c] = v;
          } else {
            if (isShared) ((float*)Cs)[(long)gr * ldc + c] = accg[mi][ni][j];
            else          Cr[((long)off + gr) * ldc + c] = f2bf(accg[mi][ni][j]);
          }
        }
      }
}

// ---------------- final combine: out = x + shared(in d_out) + sum_k w_k*yout ----------------
__global__ __launch_bounds__(256) void combine_kernel(
    const float* __restrict__ x, const float* __restrict__ sh,
    const unsigned short* __restrict__ yout, const float* __restrict__ tw,
    const int* __restrict__ pos, float* __restrict__ out) {
  int n = blockIdx.x;                  // one block per token
  int h4 = threadIdx.x << 2;           // 256 threads * 4 floats = 1024
  float4 xv = *(const float4*)(x + (long)n * HID + h4);
  float4 sv = *(const float4*)(sh + (long)n * HID + h4);   // shared-expert result (read before write)
  float a0 = xv.x + sv.x, a1 = xv.y + sv.y, a2 = xv.z + sv.z, a3 = xv.w + sv.w;
#pragma unroll
  for (int k = 0; k < 4; ++k) {
    float w = tw[n * 4 + k];
    long slot = pos[n * 4 + k];
    ushort4 yv = *(const ushort4*)(yout + slot * HID + h4);
    a0 += w * bf2f(yv.x); a1 += w * bf2f(yv.y);
    a2 += w * bf2f(yv.z); a3 += w * bf2f(yv.w);
  }
  float4 o; o.x = a0; o.y = a1; o.z = a2; o.w = a3;
  *(float4*)(out + (long)n * HID + h4) = o;
}

// ---------------- launch ----------------
extern "C" void kernel_launch(void* const* d_in, const int* in_sizes, int n_in,
                              void* d_out, int out_size, void* d_ws, size_t ws_size,
                              hipStream_t stream) {
  (void)in_sizes; (void)n_in; (void)out_size; (void)ws_size;
  const float* x   = (const float*)d_in[0];
  const float* gw  = (const float*)d_in[1];
  const float* gb  = (const float*)d_in[2];
  const float* Wg  = (const float*)d_in[3];
  const float* Wu  = (const float*)d_in[4];
  const float* Wd  = (const float*)d_in[5];
  const float* Wsg = (const float*)d_in[6];
  const float* Wsu = (const float*)d_in[7];
  const float* Wsd = (const float*)d_in[8];
  float* out = (float*)d_out;

  // ---- workspace layout (big buffers start at 512 KiB; small region ends 262400) ----
  char* w = (char*)d_ws;
  int*   counts   = (int*)(w + 0);                    // 64 B
  int*   offsets  = (int*)(w + 128);                  // 128 B (17 ints)
  int*   topk_idx = (int*)(w + 256);                  // 65536 B
  float* topk_w   = (float*)(w + 256 + 65536);        // 65536 B
  int*   perm     = (int*)(w + 256 + 131072);         // 65536 B
  int*   pos      = (int*)(w + 256 + 196608);         // 65536 B
  size_t o = 524288;                                  // big buffers from 512 KiB
  unsigned short* xb   = (unsigned short*)(w + o); o += (size_t)NTOK * HID * 2;       // 8 MB
  unsigned short* WgB  = (unsigned short*)(w + o); o += (size_t)NEXP * IMO * HID * 2; // 16 MB
  unsigned short* WuB  = (unsigned short*)(w + o); o += (size_t)NEXP * IMO * HID * 2; // 16 MB
  unsigned short* WdB  = (unsigned short*)(w + o); o += (size_t)NEXP * HID * IMO * 2; // 16 MB
  unsigned short* WsgB = (unsigned short*)(w + o); o += (size_t)SHI * HID * 2;        // 2 MB
  unsigned short* WsuB = (unsigned short*)(w + o); o += (size_t)SHI * HID * 2;        // 2 MB
  unsigned short* WsdB = (unsigned short*)(w + o); o += (size_t)HID * SHI * 2;        // 2 MB
  unsigned short* act  = (unsigned short*)(w + o); o += (size_t)NTOK * 4 * IMO * 2;   // 16 MB
  unsigned short* yout = (unsigned short*)(w + o); o += (size_t)NTOK * 4 * HID * 2;   // 32 MB
  unsigned short* sact = (unsigned short*)(w + o); o += (size_t)NTOK * SHI * 2;       // 8 MB
  // total ws use ~118.5 MiB; shared-expert fp32 output goes directly to d_out

  // convert first: warms L3 with x for gate/combine; no dependency change
  convert_all<<<31744, 256, 0, stream>>>(x, Wg, Wu, Wd, Wsg, Wsu, Wsd,
                                         xb, WgB, WuB, WdB, WsgB, WsuB, WsdB);
  gate_kernel<<<NTOK / 4, 256, 0, stream>>>(x, gw, gb, topk_idx, topk_w);
  route_kernel<<<1, 1024, 0, stream>>>(topk_idx, counts, offsets, perm, pos);
  // Level 1: shared gate+up (128 blocks: 16 mt x 8 y) + routed gate+up
  // (1024 slots: e,mt 256 x ny 4), BN=128 per matrix, 512 threads/block.
  gemm_lvl<true><<<128 + 1024, 512, 0, stream>>>(
      xb, WgB, WuB, act, HID, IMO, (long)IMO * HID, counts, offsets, perm, 1,
      xb, WsgB, WsuB, sact, NTOK, HID, SHI, 128);
  // Level 2: shared down (64 blocks: 16 mt x 4 y) + routed down
  // (1024 slots: e,mt 256 x ny 4), BN=256.
  gemm_lvl<false><<<64 + 1024, 512, 0, stream>>>(
      act, WdB, nullptr, yout, IMO, HID, (long)HID * IMO, counts, offsets, nullptr, 0,
      sact, WsdB, nullptr, out, NTOK, SHI, HID, 64);
  // out = x + shared + sum_k w_k * yout[pos]
  combine_kernel<<<NTOK, 256, 0, stream>>>(x, out, yout, topk_w, pos, out);
}